// Round 7
// baseline (451.856 us; speedup 1.0000x reference)
//
#include <hip/hip_runtime.h>

#define NVOX 262144     // 64^3
#define NB   256        // buckets = top 8 bits of lin
#define VPB  1024       // voxels per bucket = low 10 bits
#define PPB  1024       // points per block in binning passes
#define CHUNK 16384     // records per accum sorting chunk (u16 perm)
#define NBLK 256        // fallback voxel-walker blocks

// ======================= shared: padding fill ===============================
__global__ void dv_fill(const unsigned* __restrict__ nuP,
                        float* __restrict__ out, int n) {
    int nu = (int)*nuP;
    size_t meanChunks = (size_t)n * 7 / 4;
    size_t coordChunks = (size_t)n * 3 / 4;
    size_t total = meanChunks + coordChunks;
    size_t i = (size_t)blockIdx.x * blockDim.x + threadIdx.x;
    if (i >= total) return;
    float* mean = out;
    float* coords = out + (size_t)n * 7;
    if (i < meanChunks) {
        size_t base = i * 4, lim = (size_t)nu * 7;
        if (base >= lim) {
            *(float4*)(mean + base) = make_float4(0.f, 0.f, 0.f, 0.f);
        } else if (base + 4 > lim) {
            for (size_t k = lim; k < base + 4; ++k) mean[k] = 0.f;
        }
    } else {
        size_t base = (i - meanChunks) * 4, lim = (size_t)nu * 3;
        if (base >= lim) {
            *(float4*)(coords + base) = make_float4(-1.f, -1.f, -1.f, -1.f);
        } else if (base + 4 > lim) {
            for (size_t k = lim; k < base + 4; ++k) coords[k] = -1.f;
        }
    }
}

// ======================= RADIX (fat-record) PATH ============================
// P1: per-block LDS histogram over 256 buckets (coalesced global write)
__global__ void rx_hist(const int* __restrict__ gi, int n,
                        unsigned* __restrict__ blockHist) {
    __shared__ unsigned h[NB];
    int t = threadIdx.x, b = blockIdx.x;
    h[t] = 0;
    __syncthreads();
    int base = b * PPB;
#pragma unroll
    for (int k = 0; k < PPB / 256; ++k) {
        int i = base + k * 256 + t;
        if (i < n) {
            int g0 = gi[3 * i], g1 = gi[3 * i + 1];
            atomicAdd(&h[(g0 << 2) | (g1 >> 4)], 1u);
        }
    }
    __syncthreads();
    blockHist[(size_t)b * NB + t] = h[t];
}

// P2a: per-bucket totals (one block per bucket)
__global__ void rx_bucketsum(const unsigned* __restrict__ blockHist, int nb1,
                             unsigned* __restrict__ bucketCount) {
    int bk = blockIdx.x, t = threadIdx.x;
    unsigned s = 0;
    for (int blk = t; blk < nb1; blk += 256) s += blockHist[(size_t)blk * NB + bk];
    __shared__ unsigned sm[256];
    sm[t] = s;
    __syncthreads();
    for (int off = 128; off > 0; off >>= 1) {
        if (t < off) sm[t] += sm[t + off];
        __syncthreads();
    }
    if (t == 0) bucketCount[bk] = sm[0];
}

// P2b / P5: exclusive scan of 256 values; out[256] = total
__global__ void rx_scan256(const unsigned* __restrict__ in,
                           unsigned* __restrict__ out) {
    __shared__ unsigned sm[NB];
    int t = threadIdx.x;
    unsigned mine = in[t];
    sm[t] = mine;
    __syncthreads();
    for (int off = 1; off < NB; off <<= 1) {
        unsigned v = (t >= off) ? sm[t - off] : 0u;
        __syncthreads();
        sm[t] += v;
        __syncthreads();
    }
    out[t] = sm[t] - mine;
    if (t == NB - 1) out[NB] = sm[t];
}

// P2c: per-bucket exclusive scan over block hists (in place, + bucketBase)
__global__ void rx_blockscan(unsigned* __restrict__ blockHist, int nb1,
                             const unsigned* __restrict__ bucketBase) {
    int bk = blockIdx.x, t = threadIdx.x;
    __shared__ unsigned sm[256];
    __shared__ unsigned carry;
    if (t == 0) carry = bucketBase[bk];
    __syncthreads();
    for (int chunk = 0; chunk * 256 < nb1; ++chunk) {
        int blk = chunk * 256 + t;
        unsigned v = (blk < nb1) ? blockHist[(size_t)blk * NB + bk] : 0u;
        sm[t] = v;
        __syncthreads();
        for (int off = 1; off < 256; off <<= 1) {
            unsigned u = (t >= off) ? sm[t - off] : 0u;
            __syncthreads();
            sm[t] += u;
            __syncthreads();
        }
        if (blk < nb1) blockHist[(size_t)blk * NB + bk] = carry + sm[t] - v;
        __syncthreads();
        if (t == 255) carry += sm[255];
        __syncthreads();
    }
}

// P3: block-level counting-sort scatter — coalesced 32B-record bursts.
// Per 1024-pt block: stage pts in LDS (coalesced), rank points by bucket via
// LDS hist-with-return, scan -> sorted position, then lanes sweep sorted
// positions gathering rows from LDS and storing to consecutive global slots.
__global__ void __launch_bounds__(256) rx_scatter(
        const int* __restrict__ gi, const float* __restrict__ pts, int n,
        const unsigned* __restrict__ blockHist, float* __restrict__ recs) {
    __shared__ __align__(16) float ptsS[PPB * 7];   // 28672 B
    __shared__ unsigned hist[NB];                   // counts -> inclusive scan
    __shared__ unsigned bucketStart[NB];
    __shared__ unsigned runStartS[NB];
    __shared__ unsigned short perm[PPB];            // sorted pos -> local idx
    __shared__ unsigned dstsub[PPB];                // (globalDst<<10) | sub
    int t = threadIdx.x, b = blockIdx.x;
    int base = b * PPB;
    int cnt = n - base;
    if (cnt > PPB) cnt = PPB;

    hist[t] = 0;
    runStartS[t] = blockHist[(size_t)b * NB + t];   // global run starts

    // stage points: fully coalesced (7 float4 per thread when cnt==PPB)
    if (cnt == PPB) {
        const float4* src = (const float4*)(pts + (size_t)base * 7);
        float4* dstl = (float4*)ptsS;
#pragma unroll
        for (int k = 0; k < PPB * 7 / 4 / 256; ++k)
            dstl[k * 256 + t] = src[k * 256 + t];
    } else {
        for (int k = t; k < cnt * 7; k += 256)
            ptsS[k] = pts[(size_t)base * 7 + k];
    }
    __syncthreads();

    // rank: 1 LDS atomic per point
    int bkA[PPB / 256], subA[PPB / 256];
    unsigned posA[PPB / 256];
#pragma unroll
    for (int k = 0; k < PPB / 256; ++k) {
        int lid = k * 256 + t;
        if (lid < cnt) {
            int i = base + lid;
            int g0 = gi[3 * i], g1 = gi[3 * i + 1], g2 = gi[3 * i + 2];
            bkA[k] = (g0 << 2) | (g1 >> 4);
            subA[k] = ((g1 & 15) << 6) | g2;
            posA[k] = atomicAdd(&hist[bkA[k]], 1u);
        }
    }
    __syncthreads();
    // exclusive scan of hist -> bucketStart
    unsigned mine = hist[t];
    for (int off = 1; off < NB; off <<= 1) {
        unsigned v = (t >= off) ? hist[t - off] : 0u;
        __syncthreads();
        hist[t] += v;
        __syncthreads();
    }
    bucketStart[t] = hist[t] - mine;
    __syncthreads();
    // place: sorted position + packed global destination
#pragma unroll
    for (int k = 0; k < PPB / 256; ++k) {
        int lid = k * 256 + t;
        if (lid < cnt) {
            unsigned sp = bucketStart[bkA[k]] + posA[k];
            unsigned d = runStartS[bkA[k]] + posA[k];
            perm[sp] = (unsigned short)lid;
            dstsub[sp] = (d << 10) | (unsigned)subA[k];
        }
    }
    __syncthreads();
    // emit: lane j -> sorted record j; consecutive lanes hit consecutive
    // global slots within each bucket run -> coalesced dwordx4 bursts
#pragma unroll
    for (int k = 0; k < PPB / 256; ++k) {
        int j = k * 256 + t;
        if (j < cnt) {
            int lid = perm[j];
            unsigned u = dstsub[j];
            unsigned d = u >> 10, sub = u & 1023u;
            const float* r = ptsS + lid * 7;
            float f0 = r[0], f1 = r[1], f2 = r[2], f3 = r[3];
            f1or: ;
            float f4 = r[4], f5 = r[5], f6 = r[6];
            float4* o = (float4*)(recs + (size_t)d * 8);
            o[0] = make_float4(f0, f1, f2, f3);
            o[1] = make_float4(f4, f5, f6, __uint_as_float(sub));
        }
    }
}

// P4: per-bucket in-LDS counting sort (2 LDS atomics/record) + register accum
__global__ void __launch_bounds__(1024) rx_accum(
        const float* __restrict__ recs,
        const unsigned* __restrict__ bucketBase,
        float* __restrict__ accTable, unsigned* __restrict__ occCount) {
    __shared__ unsigned off[VPB];           // hist -> offsets -> cursors
    __shared__ unsigned short perm[CHUNK];  // 32 KB
    __shared__ unsigned smw[16];
    int t = threadIdx.x, bk = blockIdx.x;
    unsigned s = bucketBase[bk], e = bucketBase[bk + 1];
    float a0 = 0.f, a1 = 0.f, a2 = 0.f, a3 = 0.f,
          a4 = 0.f, a5 = 0.f, a6 = 0.f, cf = 0.f;
    for (unsigned cs = s; cs < e; cs += CHUNK) {
        unsigned ce = cs + CHUNK < e ? cs + CHUNK : e;
        off[t] = 0;
        __syncthreads();
        // phase A: histogram of sub keys (1 LDS atomic/record); warms L2
        for (unsigned i = cs + t; i < ce; i += 1024)
            atomicAdd(&off[__float_as_uint(recs[(size_t)i * 8 + 7])], 1u);
        __syncthreads();
        unsigned mine = off[t];
        // phase B: inclusive scan -> exclusive starts (Hillis-Steele)
        for (int d = 1; d < 1024; d <<= 1) {
            unsigned v = (t >= d) ? off[t - d] : 0u;
            __syncthreads();
            off[t] += v;
            __syncthreads();
        }
        off[t] -= mine;   // own slot; all cross-reads done
        __syncthreads();
        // phase C: rank (1 LDS atomic/record) + scatter u16 index into perm
        for (unsigned i = cs + t; i < ce; i += 1024) {
            unsigned sub = __float_as_uint(recs[(size_t)i * 8 + 7]);
            unsigned pos = atomicAdd(&off[sub], 1u);
            perm[pos] = (unsigned short)(i - cs);
        }
        __syncthreads();
        // phase D: thread t owns voxel t — serial atomic-free gather (L2 hits)
        unsigned start = t ? off[t - 1] : 0u;   // off[v] = end_v = start_{v+1}
        unsigned end = off[t];
        for (unsigned k = start; k < end; ++k) {
            const float4* r =
                (const float4*)(recs + ((size_t)cs + perm[k]) * 8);
            float4 lo = r[0], hi = r[1];
            a0 += lo.x; a1 += lo.y; a2 += lo.z; a3 += lo.w;
            a4 += hi.x; a5 += hi.y; a6 += hi.z; cf += 1.f;
        }
        __syncthreads();   // before off/perm reuse next chunk
    }
    float4* o = (float4*)(accTable + ((size_t)bk * VPB + t) * 8);
    o[0] = make_float4(a0, a1, a2, a3);
    o[1] = make_float4(a4, a5, a6, cf);
    unsigned long long m = __ballot(cf > 0.f);
    if ((t & 63) == 0) smw[t >> 6] = (unsigned)__popcll(m);
    __syncthreads();
    if (t == 0) {
        unsigned occ = 0;
#pragma unroll
        for (int w = 0; w < 16; ++w) occ += smw[w];
        occCount[bk] = occ;
    }
}

// P6: emit compacted means + coords from accTable
__global__ void rx_emit(const float* __restrict__ accTable,
                        const unsigned* __restrict__ rankBase,
                        float* __restrict__ out_mean,
                        float* __restrict__ out_coords) {
    int bk = blockIdx.x, t = threadIdx.x;
    float row[4][8];
    int pre[4], mycount = 0;
#pragma unroll
    for (int j = 0; j < 4; ++j) {
        int v = t * 4 + j;
        const float4* a = (const float4*)(accTable + ((size_t)bk * VPB + v) * 8);
        float4 r0 = a[0], r1 = a[1];
        row[j][0] = r0.x; row[j][1] = r0.y; row[j][2] = r0.z; row[j][3] = r0.w;
        row[j][4] = r1.x; row[j][5] = r1.y; row[j][6] = r1.z; row[j][7] = r1.w;
        pre[j] = mycount;
        mycount += (row[j][7] > 0.f) ? 1 : 0;
    }
    __shared__ int sm[256];
    sm[t] = mycount;
    __syncthreads();
    for (int off = 1; off < 256; off <<= 1) {
        int v = (t >= off) ? sm[t - off] : 0;
        __syncthreads();
        sm[t] += v;
        __syncthreads();
    }
    int rank0 = (int)rankBase[bk] + (sm[t] - mycount);
#pragma unroll
    for (int j = 0; j < 4; ++j) {
        if (row[j][7] > 0.f) {
            int r = rank0 + pre[j];
            int lin = (bk << 10) | (t * 4 + j);
            float inv = 1.0f / row[j][7];
            float* m = out_mean + (size_t)r * 7;
#pragma unroll
            for (int k = 0; k < 7; ++k) m[k] = row[j][k] * inv;
            float* cd = out_coords + (size_t)r * 3;
            cd[0] = (float)(lin >> 12);
            cd[1] = (float)((lin >> 6) & 63);
            cd[2] = (float)(lin & 63);
        }
    }
}

// ======================= FALLBACK PATH (round-3, proven) ====================
struct Meta {
    unsigned blockSums[NBLK];
    unsigned blockFlagSums[NBLK];
    unsigned blockOffs[NBLK];
    unsigned blockRankOffs[NBLK];
    unsigned nUnique;
};

__global__ void dv_count(const int* __restrict__ gi, int n,
                         unsigned* __restrict__ counts,
                         unsigned short* __restrict__ slots) {
    int i = blockIdx.x * blockDim.x + threadIdx.x;
    if (i >= n) return;
    int lin = (gi[3 * i] << 12) | (gi[3 * i + 1] << 6) | gi[3 * i + 2];
    unsigned s = atomicAdd(&counts[lin], 1u);
    slots[i] = (unsigned short)s;
}

__global__ void dv_bs1(const unsigned* __restrict__ counts,
                       Meta* __restrict__ meta) {
    int b = blockIdx.x, t = threadIdx.x;
    uint4 c = ((const uint4*)(counts + (size_t)b * 1024))[t];
    unsigned cs = c.x + c.y + c.z + c.w;
    unsigned fs = (c.x > 0) + (c.y > 0) + (c.z > 0) + (c.w > 0);
    __shared__ unsigned smC[256], smF[256];
    smC[t] = cs; smF[t] = fs;
    __syncthreads();
    for (int off = 128; off > 0; off >>= 1) {
        if (t < off) { smC[t] += smC[t + off]; smF[t] += smF[t + off]; }
        __syncthreads();
    }
    if (t == 0) { meta->blockSums[b] = smC[0]; meta->blockFlagSums[b] = smF[0]; }
}

__global__ void dv_scan2(unsigned* __restrict__ offsets, int n,
                         Meta* __restrict__ meta) {
    __shared__ unsigned smC[NBLK], smF[NBLK];
    int t = threadIdx.x;
    unsigned c = meta->blockSums[t], f = meta->blockFlagSums[t];
    smC[t] = c; smF[t] = f;
    __syncthreads();
    for (int off = 1; off < NBLK; off <<= 1) {
        unsigned vc = (t >= off) ? smC[t - off] : 0u;
        unsigned vf = (t >= off) ? smF[t - off] : 0u;
        __syncthreads();
        smC[t] += vc; smF[t] += vf;
        __syncthreads();
    }
    meta->blockOffs[t] = smC[t] - c;
    meta->blockRankOffs[t] = smF[t] - f;
    if (t == NBLK - 1) { meta->nUnique = smF[t]; offsets[NVOX] = (unsigned)n; }
}

__global__ void dv_scan3(unsigned* __restrict__ counts,
                         const Meta* __restrict__ meta) {
    int b = blockIdx.x, t = threadIdx.x;
    uint4 c = ((const uint4*)(counts + (size_t)b * 1024))[t];
    unsigned mysum = c.x + c.y + c.z + c.w;
    __shared__ unsigned sm[256];
    sm[t] = mysum;
    __syncthreads();
    for (int off = 1; off < 256; off <<= 1) {
        unsigned v = (t >= off) ? sm[t - off] : 0u;
        __syncthreads();
        sm[t] += v;
        __syncthreads();
    }
    unsigned base = meta->blockOffs[b] + sm[t] - mysum;
    uint4 o;
    o.x = base;
    o.y = base + c.x;
    o.z = o.y + c.y;
    o.w = o.z + c.z;
    ((uint4*)(counts + (size_t)b * 1024))[t] = o;
}

__global__ void dv_scatter2(const int* __restrict__ gi, int n,
                            const unsigned* __restrict__ offsets,
                            const unsigned short* __restrict__ slots,
                            unsigned* __restrict__ perm) {
    int i = blockIdx.x * blockDim.x + threadIdx.x;
    if (i >= n) return;
    int lin = (gi[3 * i] << 12) | (gi[3 * i + 1] << 6) | gi[3 * i + 2];
    perm[offsets[lin] + (unsigned)slots[i]] = (unsigned)i;
}

__global__ void dv_emit2(const float* __restrict__ points,
                         const unsigned* __restrict__ offsets,
                         const unsigned* __restrict__ perm,
                         const Meta* __restrict__ meta,
                         float* __restrict__ out_mean,
                         float* __restrict__ out_coords) {
    int b = blockIdx.x, t = threadIdx.x;
    int base = b * 1024 + t * 4;
    uint4 o4 = ((const uint4*)offsets)[b * 256 + t];
    unsigned o[5];
    o[0] = o4.x; o[1] = o4.y; o[2] = o4.z; o[3] = o4.w;
    o[4] = offsets[base + 4];
    int c[4], pre[4], mycount = 0;
#pragma unroll
    for (int j = 0; j < 4; ++j) {
        c[j] = (int)(o[j + 1] - o[j]);
        pre[j] = mycount;
        mycount += (c[j] > 0) ? 1 : 0;
    }
    __shared__ int sm[256];
    sm[t] = mycount;
    __syncthreads();
    for (int off = 1; off < 256; off <<= 1) {
        int v = (t >= off) ? sm[t - off] : 0;
        __syncthreads();
        sm[t] += v;
        __syncthreads();
    }
    int rank0 = (int)meta->blockRankOffs[b] + (sm[t] - mycount);
#pragma unroll
    for (int j = 0; j < 4; ++j) {
        if (c[j] > 0) {
            float s0 = 0.f, s1 = 0.f, s2 = 0.f, s3 = 0.f,
                  s4 = 0.f, s5 = 0.f, s6 = 0.f;
            for (unsigned k = o[j]; k < o[j + 1]; ++k) {
                unsigned idx = perm[k];
                const float* p = points + (size_t)idx * 7;
                s0 += p[0]; s1 += p[1]; s2 += p[2]; s3 += p[3];
                s4 += p[4]; s5 += p[5]; s6 += p[6];
            }
            int r = rank0 + pre[j];
            int v = base + j;
            float inv = 1.0f / (float)c[j];
            float* m = out_mean + (size_t)r * 7;
            m[0] = s0 * inv; m[1] = s1 * inv; m[2] = s2 * inv;
            m[3] = s3 * inv; m[4] = s4 * inv; m[5] = s5 * inv;
            m[6] = s6 * inv;
            float* cd = out_coords + (size_t)r * 3;
            cd[0] = (float)(v >> 12);
            cd[1] = (float)((v >> 6) & 63);
            cd[2] = (float)(v & 63);
        }
    }
}

// ======================= launch =============================================
extern "C" void kernel_launch(void* const* d_in, const int* in_sizes, int n_in,
                              void* d_out, int out_size, void* d_ws, size_t ws_size,
                              hipStream_t stream) {
    const float* points = (const float*)d_in[0];
    const int*   gi     = (const int*)d_in[1];
    int n = in_sizes[0] / 7;   // 4,000,000

    float* out_mean   = (float*)d_out;
    float* out_coords = (float*)d_out + (size_t)n * 7;

    int threads = 256;
    int nb1 = (n + PPB - 1) / PPB;

    size_t recsB = (size_t)n * 8 * sizeof(float);            // 128 MiB
    size_t bhB   = (size_t)nb1 * NB * sizeof(unsigned);      // ~4 MB
    size_t accB  = (size_t)NB * VPB * 8 * sizeof(float);     // 8 MiB
    size_t need  = recsB + bhB + (NB + 1) * 4 + accB + NB * 4 + NB * 4 +
                   (NB + 1) * 4 + 256;

    size_t fillChunks = (size_t)n * 7 / 4 + (size_t)n * 3 / 4;
    int fillBlocks = (int)((fillChunks + threads - 1) / threads);

    if (ws_size >= need) {
        char* w = (char*)d_ws;
        float*    recs        = (float*)w;                 w += recsB;
        unsigned* blockHist   = (unsigned*)w;              w += bhB;
        unsigned* bucketCount = (unsigned*)w;              w += NB * 4;
        unsigned* bucketBase  = (unsigned*)w;              w += (NB + 1) * 4;
        unsigned* occCount    = (unsigned*)w;              w += NB * 4;
        unsigned* rankBase    = (unsigned*)w;              w += (NB + 1) * 4;
        float*    accTable    = (float*)w;

        rx_hist<<<nb1, 256, 0, stream>>>(gi, n, blockHist);
        rx_bucketsum<<<NB, 256, 0, stream>>>(blockHist, nb1, bucketCount);
        rx_scan256<<<1, NB, 0, stream>>>(bucketCount, bucketBase);
        rx_blockscan<<<NB, 256, 0, stream>>>(blockHist, nb1, bucketBase);
        rx_scatter<<<nb1, 256, 0, stream>>>(gi, points, n, blockHist, recs);
        rx_accum<<<NB, 1024, 0, stream>>>(recs, bucketBase, accTable, occCount);
        rx_scan256<<<1, NB, 0, stream>>>(occCount, rankBase);
        rx_emit<<<NB, 256, 0, stream>>>(accTable, rankBase, out_mean, out_coords);
        dv_fill<<<fillBlocks, threads, 0, stream>>>(rankBase + NB,
                                                    (float*)d_out, n);
    } else {
        char* w = (char*)d_ws;
        unsigned*       perm    = (unsigned*)w;
        unsigned short* slots   = (unsigned short*)(w + (size_t)n * 4);
        unsigned*       offsets = (unsigned*)(w + (size_t)n * 4 + (size_t)n * 2);
        Meta*           meta    = (Meta*)((char*)offsets + (size_t)(NVOX + 4) * 4);

        hipMemsetAsync(offsets, 0, (size_t)(NVOX + 4) * 4, stream);

        int blocksN = (n + threads - 1) / threads;
        dv_count<<<blocksN, threads, 0, stream>>>(gi, n, offsets, slots);
        dv_bs1<<<NBLK, 256, 0, stream>>>(offsets, meta);
        dv_scan2<<<1, NBLK, 0, stream>>>(offsets, n, meta);
        dv_scan3<<<NBLK, 256, 0, stream>>>(offsets, meta);
        dv_scatter2<<<blocksN, threads, 0, stream>>>(gi, n, offsets, slots, perm);
        dv_emit2<<<NBLK, 256, 0, stream>>>(points, offsets, perm, meta,
                                           out_mean, out_coords);
        dv_fill<<<fillBlocks, threads, 0, stream>>>(&meta->nUnique,
                                                    (float*)d_out, n);
    }
}